// Round 7
// baseline (168.960 us; speedup 1.0000x reference)
//
#include <hip/hip_runtime.h>

#define NA 1000
#define NCH 3
#define CHUNK 334              // chunk lengths 334,334,332 (all even)
#define ND 513
#define ND2 512                // pair cells per angle: i0 in [0,511]
#define CROP 362
#define TOP 75                 // (512-362)/2
#define NPIX (CROP * CROP)     // 131044
#define NTILE 23               // ceil(362/16)

typedef __fp16 half2_t __attribute__((ext_vector_type(2)));

// Static device buffers, fully rewritten every call (deterministic).
// g_pair: [angle][d(512)][32 B] = pre-assembled interp pairs:
//   uint4 #0 = (f16 x[b][a][d], f16 x[b][a][d+1]) for b=0..3, #1 for b=4..7.
// g_part: [chunk][batch][pix] f32 partial sums.
__device__ float2 g_tab[NA];
__device__ uint4  g_pair[(size_t)NA * ND2 * 2];
__device__ float  g_part[(size_t)NCH * 8 * NPIX];

__global__ void table_kernel() {
    int a = blockIdx.x * blockDim.x + threadIdx.x;
    if (a >= NA) return;
    double th = (double)a * (3.14159265358979323846 / (double)NA);
    float delta_f = (float)(2.0 * 0.13 / (double)(ND - 1));
    double inv = 1.0 / (double)delta_f;
    g_tab[a] = make_float2((float)(cos(th) * inv), (float)(sin(th) * inv));
}

// x[b][a][d] (b-major, f32) -> g_pair pre-permuted f16 pairs.
__global__ void pack_kernel(const float* __restrict__ x) {
    int t = blockIdx.x * blockDim.x + threadIdx.x;   // t = a*512 + d
    if (t >= NA * ND2) return;
    int a = t >> 9, d = t & 511;
    const float* p0 = x + (size_t)a * ND + d;
    const int S = NA * ND;
    unsigned int w[8];
    #pragma unroll
    for (int b = 0; b < 8; ++b) {
        half2_t h;
        h.x = (__fp16)p0[(size_t)b * S];
        h.y = (__fp16)p0[(size_t)b * S + 1];
        __builtin_memcpy(&w[b], &h, 4);
    }
    g_pair[2 * (size_t)t]     = make_uint4(w[0], w[1], w[2], w[3]);
    g_pair[2 * (size_t)t + 1] = make_uint4(w[4], w[5], w[6], w[7]);
}

__device__ __forceinline__ float dot2(unsigned int pair, half2_t wp, float acc) {
    half2_t h; __builtin_memcpy(&h, &pair, 4);
    float d;
    asm("v_dot2_f32_f16 %0, %1, %2, %3" : "=v"(d) : "v"(h), "v"(wp), "v"(acc));
    return d;
}

// block = 256 thr; each wave owns an 8x8 pixel patch (gather span ~11 cells).
// grid = (23, 23, 3 chunks) = 1587 blocks <= 7 blocks/CU * 256 CU: all resident.
__launch_bounds__(256, 7)
__global__ void bp_kernel() {
    __shared__ float2 s_tab[CHUNK];
    int ch = blockIdx.z;
    int a0 = ch * CHUNK;
    int len = min(CHUNK, NA - a0);       // 334 or 332 (even)
    for (int t = threadIdx.x; t < len; t += 256) s_tab[t] = g_tab[a0 + t];
    __syncthreads();

    int wave = threadIdx.x >> 6;
    int lane = threadIdx.x & 63;
    int ti = (wave >> 1) * 8 + (lane >> 3);
    int tj = (wave & 1) * 8 + (lane & 7);
    int i = blockIdx.y * 16 + ti;      // -> X
    int j = blockIdx.x * 16 + tj;      // -> Y
    int ic = min(i, CROP - 1);
    int jc = min(j, CROP - 1);

    const float step = (float)(0.26 / 511.0);
    float X = fmaf((float)(TOP + ic), step, -0.13f);
    float Y = fmaf((float)(TOP + jc), step, -0.13f);

    const uint4* __restrict__ pbase = g_pair + ((size_t)a0 << 10);

    // weight + uint4-index for angle a (p in [0.23,511.77]: always in-bounds)
    auto mk = [&](int a, half2_t& wp) -> int {
        float2 cs = s_tab[a];
        float p  = fmaf(X, cs.x, fmaf(Y, cs.y, 256.0f));
        float fi = floorf(p);
        wp = __builtin_amdgcn_cvt_pkrtz(fi - p + 1.0f, p - fi);  // (1-w, w)
        return ((a << 9) + (int)fi) << 1;
    };

    float acc0 = 0.f, acc1 = 0.f, acc2 = 0.f, acc3 = 0.f;
    float acc4 = 0.f, acc5 = 0.f, acc6 = 0.f, acc7 = 0.f;

    // ---- depth-2, two-angle-wide software pipeline ----
    half2_t w0, w1;
    int o0 = mk(0, w0);
    int o1 = mk(1, w1);
    uint4 A0 = pbase[o0], B0 = pbase[o0 + 1];
    uint4 A1 = pbase[o1], B1 = pbase[o1 + 1];

    #pragma unroll 2
    for (int a = 0; a < len; a += 2) {
        // issue loads for angles a+2, a+3 (clamped; extras discarded post-loop)
        int n0 = min(a + 2, len - 1);
        int n1 = min(a + 3, len - 1);
        half2_t nw0, nw1;
        int q0 = mk(n0, nw0);
        int q1 = mk(n1, nw1);
        uint4 tA0 = pbase[q0], tB0 = pbase[q0 + 1];
        uint4 tA1 = pbase[q1], tB1 = pbase[q1 + 1];

        // consume angle a
        acc0 = dot2(A0.x, w0, acc0);
        acc1 = dot2(A0.y, w0, acc1);
        acc2 = dot2(A0.z, w0, acc2);
        acc3 = dot2(A0.w, w0, acc3);
        acc4 = dot2(B0.x, w0, acc4);
        acc5 = dot2(B0.y, w0, acc5);
        acc6 = dot2(B0.z, w0, acc6);
        acc7 = dot2(B0.w, w0, acc7);
        // consume angle a+1 (len is even)
        acc0 = dot2(A1.x, w1, acc0);
        acc1 = dot2(A1.y, w1, acc1);
        acc2 = dot2(A1.z, w1, acc2);
        acc3 = dot2(A1.w, w1, acc3);
        acc4 = dot2(B1.x, w1, acc4);
        acc5 = dot2(B1.y, w1, acc5);
        acc6 = dot2(B1.z, w1, acc6);
        acc7 = dot2(B1.w, w1, acc7);

        A0 = tA0; B0 = tB0; w0 = nw0;
        A1 = tA1; B1 = tB1; w1 = nw1;
    }

    if (i < CROP && j < CROP) {
        float* p0 = g_part + (size_t)ch * 8 * NPIX + (size_t)i * CROP + j;
        p0[0 * NPIX] = acc0; p0[1 * NPIX] = acc1;
        p0[2 * NPIX] = acc2; p0[3 * NPIX] = acc3;
        p0[4 * NPIX] = acc4; p0[5 * NPIX] = acc5;
        p0[6 * NPIX] = acc6; p0[7 * NPIX] = acc7;
    }
}

// out[b][pix] = sum_ch part[ch][b][pix] * pi/NA
__global__ void combine_kernel(float* __restrict__ out) {
    int t = blockIdx.x * 256 + threadIdx.x;      // t over 8*NPIX, batch-major
    if (t >= 8 * NPIX) return;
    const float scale = (float)(3.14159265358979323846 / 1000.0);
    float s = 0.f;
    #pragma unroll
    for (int ch = 0; ch < NCH; ++ch) s += g_part[(size_t)ch * 8 * NPIX + t];
    out[t] = s * scale;
}

extern "C" void kernel_launch(void* const* d_in, const int* in_sizes, int n_in,
                              void* d_out, int out_size, void* d_ws, size_t ws_size,
                              hipStream_t stream) {
    const float* x = (const float*)d_in[0];
    float* out = (float*)d_out;

    table_kernel<<<(NA + 255) / 256, 256, 0, stream>>>();
    pack_kernel<<<(NA * ND2 + 255) / 256, 256, 0, stream>>>(x);

    dim3 bgrid(NTILE, NTILE, NCH);
    bp_kernel<<<bgrid, 256, 0, stream>>>();

    combine_kernel<<<(8 * NPIX + 255) / 256, 256, 0, stream>>>(out);
}

// Round 8
// 159.543 us; speedup vs baseline: 1.0590x; 1.0590x over previous
//
#include <hip/hip_runtime.h>

#define NA 1000
#define NCH 2
#define CHUNK 500              // angles per chunk
#define ND 513
#define CROP 362
#define TOP 75                 // (512-362)/2
#define NPIX (CROP * CROP)     // 131044
#define NTILE 23               // ceil(362/16)
#define GRP 20                 // angles per staged group
#define NGRP 25                // CHUNK / GRP
#define WIN 32                 // detector cells per staged window
#define SLOTS (GRP * WIN)      // 640 cells per LDS buffer

typedef __fp16 half2_t __attribute__((ext_vector_type(2)));

// Static device buffers, fully rewritten every call (deterministic).
// g_cell: [angle][det] 16 B = 8 f16 batch values (b0|b1, b2|b3, b4|b5, b6|b7).
__device__ float2 g_tab[NA];                 // (cos, sin) * 1/delta
__device__ uint4  g_cell[(size_t)NA * ND];
__device__ float  g_part[(size_t)NCH * 8 * NPIX];

__global__ void table_kernel() {
    int a = blockIdx.x * blockDim.x + threadIdx.x;
    if (a >= NA) return;
    double th = (double)a * (3.14159265358979323846 / (double)NA);
    float delta_f = (float)(2.0 * 0.13 / (double)(ND - 1));
    double inv = 1.0 / (double)delta_f;
    g_tab[a] = make_float2((float)(cos(th) * inv), (float)(sin(th) * inv));
}

// x[b][a][d] (b-major, f32) -> g_cell (8 f16 per det), RNE.
__global__ void pack_kernel(const float* __restrict__ x) {
    int t = blockIdx.x * blockDim.x + threadIdx.x;   // t = a*ND + d
    if (t >= NA * ND) return;
    const int S = NA * ND;
    unsigned int w[4];
    #pragma unroll
    for (int b = 0; b < 4; ++b) {
        half2_t h;
        h.x = (__fp16)x[(size_t)(2 * b) * S + t];
        h.y = (__fp16)x[(size_t)(2 * b + 1) * S + t];
        __builtin_memcpy(&w[b], &h, 4);
    }
    g_cell[t] = make_uint4(w[0], w[1], w[2], w[3]);
}

__device__ __forceinline__ float dot2(unsigned int pair, half2_t wp, float acc) {
    half2_t h; __builtin_memcpy(&h, &pair, 4);
    float d;
    asm("v_dot2_f32_f16 %0, %1, %2, %3" : "=v"(d) : "v"(h), "v"(wp), "v"(acc));
    return d;
}

// grid = (23, 23, 2); block = 256. Wave = 8x8 pixel patch. Per block: 16x16
// pixel tile x 500 angles, windows staged in LDS, double-buffered.
__global__ __launch_bounds__(256, 5) void bp_kernel() {
    __shared__ uint4 s_buf[2 * SLOTS];   // 20 KB
    __shared__ int   s_base[CHUNK];      // 2 KB

    int ch  = blockIdx.z;
    int A0  = ch * CHUNK;
    int tid = threadIdx.x;
    int bi  = blockIdx.y, bj = blockIdx.x;

    const float step = (float)(0.26 / 511.0);

    // ---- per-angle window bases (corner-min p, 2-cell guard) ----
    float Xa = fmaf((float)(TOP + bi * 16),      step, -0.13f);
    float Xb = fmaf((float)(TOP + bi * 16 + 15), step, -0.13f);
    float Ya = fmaf((float)(TOP + bj * 16),      step, -0.13f);
    float Yb = fmaf((float)(TOP + bj * 16 + 15), step, -0.13f);
    for (int aidx = tid; aidx < CHUNK; aidx += 256) {
        float2 cs = g_tab[A0 + aidx];
        float p0 = fmaf(Xa, cs.x, fmaf(Ya, cs.y, 256.0f));
        float p1 = fmaf(Xb, cs.x, fmaf(Ya, cs.y, 256.0f));
        float p2 = fmaf(Xa, cs.x, fmaf(Yb, cs.y, 256.0f));
        float p3 = fmaf(Xb, cs.x, fmaf(Yb, cs.y, 256.0f));
        float pm = fminf(fminf(p0, p1), fminf(p2, p3)) - 2.0f;
        int b = (int)floorf(pm);
        b = b < 0 ? 0 : b;
        b = b > (ND - WIN) ? (ND - WIN) : b;   // 481: window [b, b+31] <= 512
        s_base[aidx] = b;
    }
    __syncthreads();

    // ---- stage group 0 into buffer 0 ----
    {
        int s0 = tid, s1 = tid + 256, s2 = tid + 512;
        uint4 t0 = g_cell[(size_t)(A0 + (s0 >> 5)) * ND + s_base[s0 >> 5] + (s0 & 31)];
        uint4 t1 = g_cell[(size_t)(A0 + (s1 >> 5)) * ND + s_base[s1 >> 5] + (s1 & 31)];
        uint4 t2 = {};
        if (tid < 128)
            t2 = g_cell[(size_t)(A0 + (s2 >> 5)) * ND + s_base[s2 >> 5] + (s2 & 31)];
        s_buf[s0] = t0;
        s_buf[s1] = t1;
        if (tid < 128) s_buf[s2] = t2;
    }
    __syncthreads();

    // ---- per-thread pixel coords ----
    int wave = tid >> 6, lane = tid & 63;
    int i = bi * 16 + (wave >> 1) * 8 + (lane >> 3);   // -> X
    int j = bj * 16 + (wave & 1) * 8 + (lane & 7);     // -> Y
    int ic = min(i, CROP - 1), jc = min(j, CROP - 1);
    float X = fmaf((float)(TOP + ic), step, -0.13f);
    float Y = fmaf((float)(TOP + jc), step, -0.13f);

    // ---- 4 rotation chains for (cos,sin)*inv, step 4*dtheta each ----
    double dth  = 3.14159265358979323846 / 1000.0;
    float delta_f = (float)(2.0 * 0.13 / (double)(ND - 1));
    double invd = 1.0 / (double)delta_f;
    float c0 = (float)(cos((A0 + 0) * dth) * invd), s0r = (float)(sin((A0 + 0) * dth) * invd);
    float c1 = (float)(cos((A0 + 1) * dth) * invd), s1r = (float)(sin((A0 + 1) * dth) * invd);
    float c2 = (float)(cos((A0 + 2) * dth) * invd), s2r = (float)(sin((A0 + 2) * dth) * invd);
    float c3 = (float)(cos((A0 + 3) * dth) * invd), s3r = (float)(sin((A0 + 3) * dth) * invd);
    float C4 = (float)cos(4.0 * dth), S4 = (float)sin(4.0 * dth);

    float acc0 = 0.f, acc1 = 0.f, acc2 = 0.f, acc3 = 0.f;
    float acc4 = 0.f, acc5 = 0.f, acc6 = 0.f, acc7 = 0.f;

#define BODY(K, BASE, CC, SS)                                                   \
    {                                                                           \
        float p  = fmaf(X, CC, fmaf(Y, SS, 256.0f));                            \
        float fi = floorf(p);                                                   \
        half2_t wp = __builtin_amdgcn_cvt_pkrtz(fi - p + 1.0f, p - fi);         \
        int l = (int)fi - (BASE);                                               \
        const uint4* cc_ = cb + ((q4 + K) * WIN + l);                           \
        uint4 Ac = cc_[0], Bc = cc_[1];                                         \
        acc0 = dot2(__builtin_amdgcn_perm(Bc.x, Ac.x, 0x05040100u), wp, acc0);  \
        acc1 = dot2(__builtin_amdgcn_perm(Bc.x, Ac.x, 0x07060302u), wp, acc1);  \
        acc2 = dot2(__builtin_amdgcn_perm(Bc.y, Ac.y, 0x05040100u), wp, acc2);  \
        acc3 = dot2(__builtin_amdgcn_perm(Bc.y, Ac.y, 0x07060302u), wp, acc3);  \
        acc4 = dot2(__builtin_amdgcn_perm(Bc.z, Ac.z, 0x05040100u), wp, acc4);  \
        acc5 = dot2(__builtin_amdgcn_perm(Bc.z, Ac.z, 0x07060302u), wp, acc5);  \
        acc6 = dot2(__builtin_amdgcn_perm(Bc.w, Ac.w, 0x05040100u), wp, acc6);  \
        acc7 = dot2(__builtin_amdgcn_perm(Bc.w, Ac.w, 0x07060302u), wp, acc7);  \
        float oc = CC, os = SS;                                                 \
        float m1 = os * S4; CC = fmaf(oc, C4, -m1);                             \
        float m2 = os * C4; SS = fmaf(oc, S4, m2);                              \
    }

    for (int g = 0; g < NGRP; ++g) {
        // issue next group's staging loads (consumed after the compute phase)
        uint4 t0 = {}, t1 = {}, t2 = {};
        bool have = (g + 1) < NGRP;
        if (have) {
            int gg = (g + 1) * GRP;
            int s0 = tid, s1 = tid + 256, s2 = tid + 512;
            t0 = g_cell[(size_t)(A0 + gg + (s0 >> 5)) * ND + s_base[gg + (s0 >> 5)] + (s0 & 31)];
            t1 = g_cell[(size_t)(A0 + gg + (s1 >> 5)) * ND + s_base[gg + (s1 >> 5)] + (s1 & 31)];
            if (tid < 128)
                t2 = g_cell[(size_t)(A0 + gg + (s2 >> 5)) * ND + s_base[gg + (s2 >> 5)] + (s2 & 31)];
        }

        const uint4* cb = s_buf + (g & 1) * SLOTS;
        int gb = g * GRP;
        #pragma unroll
        for (int q = 0; q < 5; ++q) {
            int q4 = q * 4;
            int4 b4 = *(const int4*)(s_base + gb + q4);   // uniform broadcast
            BODY(0, b4.x, c0, s0r)
            BODY(1, b4.y, c1, s1r)
            BODY(2, b4.z, c2, s2r)
            BODY(3, b4.w, c3, s3r)
        }

        if (have) {
            int dst = ((g + 1) & 1) * SLOTS;
            s_buf[dst + tid] = t0;
            s_buf[dst + tid + 256] = t1;
            if (tid < 128) s_buf[dst + tid + 512] = t2;
        }
        __syncthreads();
    }
#undef BODY

    if (i < CROP && j < CROP) {
        float* p0 = g_part + (size_t)ch * 8 * NPIX + (size_t)i * CROP + j;
        p0[0 * NPIX] = acc0; p0[1 * NPIX] = acc1;
        p0[2 * NPIX] = acc2; p0[3 * NPIX] = acc3;
        p0[4 * NPIX] = acc4; p0[5 * NPIX] = acc5;
        p0[6 * NPIX] = acc6; p0[7 * NPIX] = acc7;
    }
}

// out[b][pix] = sum_ch part[ch][b][pix] * pi/NA
__global__ void combine_kernel(float* __restrict__ out) {
    int t = blockIdx.x * 256 + threadIdx.x;      // t over 8*NPIX, batch-major
    if (t >= 8 * NPIX) return;
    const float scale = (float)(3.14159265358979323846 / 1000.0);
    float s = 0.f;
    #pragma unroll
    for (int ch = 0; ch < NCH; ++ch) s += g_part[(size_t)ch * 8 * NPIX + t];
    out[t] = s * scale;
}

extern "C" void kernel_launch(void* const* d_in, const int* in_sizes, int n_in,
                              void* d_out, int out_size, void* d_ws, size_t ws_size,
                              hipStream_t stream) {
    const float* x = (const float*)d_in[0];
    float* out = (float*)d_out;

    table_kernel<<<(NA + 255) / 256, 256, 0, stream>>>();
    pack_kernel<<<(NA * ND + 255) / 256, 256, 0, stream>>>(x);

    dim3 bgrid(NTILE, NTILE, NCH);
    bp_kernel<<<bgrid, 256, 0, stream>>>();

    combine_kernel<<<(8 * NPIX + 255) / 256, 256, 0, stream>>>(out);
}

// Round 9
// 124.045 us; speedup vs baseline: 1.3621x; 1.2862x over previous
//
#include <hip/hip_runtime.h>

#define NA 1000
#define NCH 4
#define CHMAX 256              // angles per chunk: 256,256,256,232
#define ND 513
#define ND2 512                // pair cells per angle: d in [0,511]
#define CROP 362
#define TOP 75                 // (512-362)/2
#define NPIX (CROP * CROP)     // 131044
#define NTILE 23               // ceil(362/16)
#define GRP 8                  // angles per staged group (len always % 8 == 0)
#define WIN 32                 // detector cells per staged window

typedef __fp16 half2_t __attribute__((ext_vector_type(2)));

// Static device buffers, fully rewritten every call (deterministic).
// g_plo[a*512+d] = 16 B: f16 pairs (x[b][a][d], x[b][a][d+1]) for b=0..3.
// g_phi: same for b=4..7.  g_part: [chunk][batch][pix] f32 partials.
__device__ float2 g_tab[NA];
__device__ uint4  g_plo[(size_t)NA * ND2];
__device__ uint4  g_phi[(size_t)NA * ND2];
__device__ float  g_part[(size_t)NCH * 8 * NPIX];

__global__ void table_kernel() {
    int a = blockIdx.x * blockDim.x + threadIdx.x;
    if (a >= NA) return;
    double th = (double)a * (3.14159265358979323846 / (double)NA);
    float delta_f = (float)(2.0 * 0.13 / (double)(ND - 1));
    double inv = 1.0 / (double)delta_f;
    g_tab[a] = make_float2((float)(cos(th) * inv), (float)(sin(th) * inv));
}

// x[b][a][d] (b-major, f32) -> pre-assembled f16 interp pairs.
__global__ void pack_kernel(const float* __restrict__ x) {
    int t = blockIdx.x * blockDim.x + threadIdx.x;   // t = a*512 + d
    if (t >= NA * ND2) return;
    int a = t >> 9, d = t & 511;
    const float* p0 = x + (size_t)a * ND + d;
    const int S = NA * ND;
    unsigned int lo[4], hi[4];
    #pragma unroll
    for (int b = 0; b < 4; ++b) {
        half2_t h;
        h.x = (__fp16)p0[(size_t)b * S];
        h.y = (__fp16)p0[(size_t)b * S + 1];
        __builtin_memcpy(&lo[b], &h, 4);
        half2_t g;
        g.x = (__fp16)p0[(size_t)(b + 4) * S];
        g.y = (__fp16)p0[(size_t)(b + 4) * S + 1];
        __builtin_memcpy(&hi[b], &g, 4);
    }
    g_plo[t] = make_uint4(lo[0], lo[1], lo[2], lo[3]);
    g_phi[t] = make_uint4(hi[0], hi[1], hi[2], hi[3]);
}

__device__ __forceinline__ float dot2(unsigned int pair, half2_t wp, float acc) {
    half2_t h; __builtin_memcpy(&h, &pair, 4);
    float d;
    asm("v_dot2_f32_f16 %0, %1, %2, %3" : "=v"(d) : "v"(h), "v"(wp), "v"(acc));
    return d;
}

// grid (23,23,4), block 256; wave = 8x8 pixel patch; 16x16 tile per block.
// LDS: double-buffered 8-angle x 32-cell pair windows, lo/hi split = 17 KB.
__global__ __launch_bounds__(256, 8) void bp_kernel() {
    __shared__ uint4 s_lo[2][GRP * WIN];   // 8 KB
    __shared__ uint4 s_hi[2][GRP * WIN];   // 8 KB
    __shared__ int   s_base[CHMAX];        // 1 KB

    int ch  = blockIdx.z;
    int A0  = ch << 8;
    int len = min(CHMAX, NA - A0);         // 256 or 232 (both % 8 == 0)
    int ngrp = len >> 3;
    int tid = threadIdx.x;
    int bi  = blockIdx.y, bj = blockIdx.x;

    const float step = (float)(0.26 / 511.0);

    // ---- per-angle window bases (corner-min p, 2-cell guard) ----
    float Xa = fmaf((float)(TOP + bi * 16),      step, -0.13f);
    float Xb = fmaf((float)(TOP + bi * 16 + 15), step, -0.13f);
    float Ya = fmaf((float)(TOP + bj * 16),      step, -0.13f);
    float Yb = fmaf((float)(TOP + bj * 16 + 15), step, -0.13f);
    for (int aidx = tid; aidx < len; aidx += 256) {
        float2 cs = g_tab[A0 + aidx];
        float p0 = fmaf(Xa, cs.x, fmaf(Ya, cs.y, 256.0f));
        float p1 = fmaf(Xb, cs.x, fmaf(Ya, cs.y, 256.0f));
        float p2 = fmaf(Xa, cs.x, fmaf(Yb, cs.y, 256.0f));
        float p3 = fmaf(Xb, cs.x, fmaf(Yb, cs.y, 256.0f));
        float pm = fminf(fminf(p0, p1), fminf(p2, p3)) - 2.0f;
        int b = (int)floorf(pm);
        b = b < 0 ? 0 : b;
        b = b > (ND2 - WIN) ? (ND2 - WIN) : b;   // [0, 480]
        s_base[aidx] = b;
    }
    __syncthreads();

    // ---- pixel coords ----
    int wave = tid >> 6, lane = tid & 63;
    int i = bi * 16 + (wave >> 1) * 8 + (lane >> 3);   // -> X
    int j = bj * 16 + (wave & 1) * 8 + (lane & 7);     // -> Y
    int ic = min(i, CROP - 1), jc = min(j, CROP - 1);
    float X = fmaf((float)(TOP + ic), step, -0.13f);
    float Y = fmaf((float)(TOP + jc), step, -0.13f);

    // ---- 4 rotation chains for (cos,sin)*inv, each stepping 4*dtheta ----
    double dth = 3.14159265358979323846 / 1000.0;
    float delta_f = (float)(2.0 * 0.13 / (double)(ND - 1));
    double invd = 1.0 / (double)delta_f;
    float c0 = (float)(cos((A0 + 0) * dth) * invd), s0r = (float)(sin((A0 + 0) * dth) * invd);
    float c1 = (float)(cos((A0 + 1) * dth) * invd), s1r = (float)(sin((A0 + 1) * dth) * invd);
    float c2 = (float)(cos((A0 + 2) * dth) * invd), s2r = (float)(sin((A0 + 2) * dth) * invd);
    float c3 = (float)(cos((A0 + 3) * dth) * invd), s3r = (float)(sin((A0 + 3) * dth) * invd);
    float C4 = (float)cos(4.0 * dth), S4 = (float)sin(4.0 * dth);

    // staging address pieces (thread t stages cell l of group-angle k)
    int sk = tid >> 5, sl = tid & 31;

    // ---- prologue: stage group 0 into buffer 0 ----
    {
        size_t idx = (size_t)(A0 + sk) * ND2 + s_base[sk] + sl;
        s_lo[0][tid] = g_plo[idx];
        s_hi[0][tid] = g_phi[idx];
    }
    __syncthreads();

    float acc0 = 0.f, acc1 = 0.f, acc2 = 0.f, acc3 = 0.f;
    float acc4 = 0.f, acc5 = 0.f, acc6 = 0.f, acc7 = 0.f;

#define BODY(K, BASE, CC, SS)                                           \
    {                                                                   \
        float p  = fmaf(X, CC, fmaf(Y, SS, 256.0f));                    \
        float fi = floorf(p);                                           \
        half2_t wp = __builtin_amdgcn_cvt_pkrtz(fi - p + 1.0f, p - fi); \
        int l = (int)fi - (BASE);                                       \
        uint4 lo = blo[(K) * WIN + l];                                  \
        uint4 hi = bhi[(K) * WIN + l];                                  \
        acc0 = dot2(lo.x, wp, acc0);                                    \
        acc1 = dot2(lo.y, wp, acc1);                                    \
        acc2 = dot2(lo.z, wp, acc2);                                    \
        acc3 = dot2(lo.w, wp, acc3);                                    \
        acc4 = dot2(hi.x, wp, acc4);                                    \
        acc5 = dot2(hi.y, wp, acc5);                                    \
        acc6 = dot2(hi.z, wp, acc6);                                    \
        acc7 = dot2(hi.w, wp, acc7);                                    \
        float oc = CC, os = SS;                                         \
        float m1 = os * S4; CC = fmaf(oc, C4, -m1);                     \
        float m2 = os * C4; SS = fmaf(oc, S4, m2);                      \
    }

    for (int g = 0; g < ngrp; ++g) {
        int cur = g & 1;
        bool have = (g + 1) < ngrp;
        uint4 r0, r1;
        if (have) {
            int ag = (g + 1) * GRP + sk;
            size_t idx = (size_t)(A0 + ag) * ND2 + s_base[ag] + sl;
            r0 = g_plo[idx];
            r1 = g_phi[idx];
        }

        const uint4* blo = s_lo[cur];
        const uint4* bhi = s_hi[cur];
        int gb = g * GRP;
        #pragma unroll
        for (int q = 0; q < 2; ++q) {
            int4 b4 = *(const int4*)(s_base + gb + q * 4);   // uniform
            BODY(q * 4 + 0, b4.x, c0, s0r)
            BODY(q * 4 + 1, b4.y, c1, s1r)
            BODY(q * 4 + 2, b4.z, c2, s2r)
            BODY(q * 4 + 3, b4.w, c3, s3r)
        }

        if (have) {
            int nxt = cur ^ 1;
            s_lo[nxt][tid] = r0;
            s_hi[nxt][tid] = r1;
        }
        __syncthreads();
    }
#undef BODY

    if (i < CROP && j < CROP) {
        float* p0 = g_part + (size_t)ch * 8 * NPIX + (size_t)i * CROP + j;
        p0[0 * NPIX] = acc0; p0[1 * NPIX] = acc1;
        p0[2 * NPIX] = acc2; p0[3 * NPIX] = acc3;
        p0[4 * NPIX] = acc4; p0[5 * NPIX] = acc5;
        p0[6 * NPIX] = acc6; p0[7 * NPIX] = acc7;
    }
}

// out[b][pix] = sum_ch part[ch][b][pix] * pi/NA
__global__ void combine_kernel(float* __restrict__ out) {
    int t = blockIdx.x * 256 + threadIdx.x;      // t over 8*NPIX, batch-major
    if (t >= 8 * NPIX) return;
    const float scale = (float)(3.14159265358979323846 / 1000.0);
    float s = 0.f;
    #pragma unroll
    for (int ch = 0; ch < NCH; ++ch) s += g_part[(size_t)ch * 8 * NPIX + t];
    out[t] = s * scale;
}

extern "C" void kernel_launch(void* const* d_in, const int* in_sizes, int n_in,
                              void* d_out, int out_size, void* d_ws, size_t ws_size,
                              hipStream_t stream) {
    const float* x = (const float*)d_in[0];
    float* out = (float*)d_out;

    table_kernel<<<(NA + 255) / 256, 256, 0, stream>>>();
    pack_kernel<<<(NA * ND2 + 255) / 256, 256, 0, stream>>>(x);

    dim3 bgrid(NTILE, NTILE, NCH);
    bp_kernel<<<bgrid, 256, 0, stream>>>();

    combine_kernel<<<(8 * NPIX + 255) / 256, 256, 0, stream>>>(out);
}